// Round 1
// baseline (4043.438 us; speedup 1.0000x reference)
//
#include <hip/hip_runtime.h>
#include <math.h>

// Problem constants
#define BATCH 32768
#define ISZ   256
#define HSZ   512

// Static device scratch (avoids depending on ws_size):
// g_h1: h1 after cell1, then reused as htmp during RK
// g_h2: new_h (needed through all RK stages)
// g_u : tanh(W1 h + b1) intermediate
static __device__ float g_h1[(size_t)BATCH * HSZ];
static __device__ float g_h2[(size_t)BATCH * HSZ];
static __device__ float g_u [(size_t)BATCH * HSZ];

__device__ __forceinline__ float fsigm(float x) { return 1.0f / (1.0f + __expf(-x)); }
__device__ __forceinline__ float ftanh(float x) { return 1.0f - 2.0f / (__expf(2.0f * x) + 1.0f); }

// ---------------------------------------------------------------------------
// Cell kernel: z = [x|h] @ [Wih|Whh]^T + bih + bhh ; gates -> h_out, c_out
// Block tile: 64 rows (m) x 32 cols (j) x 4 gates = 64 x 128 virtual cols.
// Virtual col v = jloc*4 + g  (jloc in [0,32), g in [0,4)), W row n = g*512 + jb*32 + jloc.
// Thread microtile: 4 rows x 8 virtual cols (= 2 j x 4 gates). 256 threads.
// FIRST: h_in=h0, c_in=c0, h_out=g_h1. !FIRST: h_in=g_h1, c_in=c_io, h_out=g_h2.
// ---------------------------------------------------------------------------
template <bool FIRST>
__global__ __launch_bounds__(256) void cell_kernel(
    const float* __restrict__ x, const float* __restrict__ h0,
    const float* __restrict__ c0, const float* __restrict__ Wih,
    const float* __restrict__ Whh, const float* __restrict__ bih,
    const float* __restrict__ bhh, float* __restrict__ c_io)
{
    const int tid = threadIdx.x;
    const int mBase = blockIdx.x * 64;
    const int jb = blockIdx.y;  // 0..15, 32 j-columns per block

    __shared__ float As[32][64];    // [k][m]
    __shared__ float Ws[32][128];   // [k][v]

    const float* __restrict__ h_in = FIRST ? h0 : g_h1;
    const float* __restrict__ c_in = FIRST ? c0 : c_io;
    float* __restrict__ h_out = FIRST ? g_h1 : g_h2;

    float acc[4][8];
#pragma unroll
    for (int r = 0; r < 4; ++r)
#pragma unroll
        for (int c = 0; c < 8; ++c) acc[r][c] = 0.0f;

    const int m0 = (tid & 15) * 4;      // row base in tile
    const int v0 = (tid >> 4) * 8;      // virtual col base

    // loader mapping
    const int lm = tid >> 2;            // A row 0..63
    const int lk = (tid & 3) * 8;       // A col base (8 elems)
    const int wr = tid >> 1;            // W virtual row 0..127
    const int wk = (tid & 1) * 16;      // W col base (16 elems)
    const int wn = (wr & 3) * 512 + jb * 32 + (wr >> 2);  // global W row

    for (int kt = 0; kt < 24; ++kt) {
        const int k0 = kt * 32;
        // load A tile (x for k<256, h for k>=256)
        const float* Asrc = (k0 < 256)
            ? (x    + (size_t)(mBase + lm) * ISZ + k0 + lk)
            : (h_in + (size_t)(mBase + lm) * HSZ + (k0 - 256) + lk);
#pragma unroll
        for (int i = 0; i < 8; ++i) As[lk + i][lm] = Asrc[i];
        // load W tile
        const float* Wsrc = (k0 < 256)
            ? (Wih + (size_t)wn * ISZ + k0 + wk)
            : (Whh + (size_t)wn * HSZ + (k0 - 256) + wk);
#pragma unroll
        for (int i = 0; i < 16; ++i) Ws[wk + i][wr] = Wsrc[i];
        __syncthreads();
#pragma unroll
        for (int k = 0; k < 32; ++k) {
            float4 a  = *(const float4*)&As[k][m0];
            float4 w0 = *(const float4*)&Ws[k][v0];
            float4 w1 = *(const float4*)&Ws[k][v0 + 4];
            const float av[4] = {a.x, a.y, a.z, a.w};
            const float wv[8] = {w0.x, w0.y, w0.z, w0.w, w1.x, w1.y, w1.z, w1.w};
#pragma unroll
            for (int r = 0; r < 4; ++r)
#pragma unroll
                for (int c = 0; c < 8; ++c) acc[r][c] += av[r] * wv[c];
        }
        __syncthreads();
    }

    // epilogue: gates
#pragma unroll
    for (int r = 0; r < 4; ++r) {
        const int m = mBase + m0 + r;
#pragma unroll
        for (int jl = 0; jl < 2; ++jl) {
            const int j = jb * 32 + (v0 >> 2) + jl;
            const float zi = acc[r][jl * 4 + 0] + bih[j]        + bhh[j];
            const float zf = acc[r][jl * 4 + 1] + bih[512  + j] + bhh[512  + j];
            const float zg = acc[r][jl * 4 + 2] + bih[1024 + j] + bhh[1024 + j];
            const float zo = acc[r][jl * 4 + 3] + bih[1536 + j] + bhh[1536 + j];
            const float ig = fsigm(zi);
            const float fg = fsigm(zf);
            const float gg = ftanh(zg);
            const float og = fsigm(zo);
            const int idx = m * HSZ + j;
            const float cold = c_in[idx];
            const float cnew = fg * cold + ig * gg;
            const float hnew = og * ftanh(cnew);
            h_out[idx] = hnew;
            c_io[idx]  = cnew;
        }
    }
}

// ---------------------------------------------------------------------------
// ODE kernels. MODE 0: u = tanh(g_h2 @ W1^T + b1)
//             MODE 1: u = tanh(g_h1(htmp) @ W1^T + b1)
//             MODE 11..14: k_i = g_u @ W2^T + b2 ; RK accumulate + htmp update
// Block tile 64 rows x 128 cols, thread 4x8. 256 threads.
// ---------------------------------------------------------------------------
template <int MODE>
__global__ __launch_bounds__(256) void ode_kernel(
    const float* __restrict__ W, const float* __restrict__ b,
    const float* __restrict__ ts, float* __restrict__ accht)
{
    const int tid = threadIdx.x;
    const int mBase = blockIdx.x * 64;
    const int nBase = blockIdx.y * 128;

    __shared__ float As[32][64];
    __shared__ float Ws[32][128];

    const float* __restrict__ A = (MODE == 0) ? g_h2 : (MODE == 1) ? g_h1 : g_u;

    float acc[4][8];
#pragma unroll
    for (int r = 0; r < 4; ++r)
#pragma unroll
        for (int c = 0; c < 8; ++c) acc[r][c] = 0.0f;

    const int m0 = (tid & 15) * 4;
    const int v0 = (tid >> 4) * 8;
    const int lm = tid >> 2;
    const int lk = (tid & 3) * 8;
    const int wr = tid >> 1;
    const int wk = (tid & 1) * 16;

    const float* Arow = A + (size_t)(mBase + lm) * HSZ + lk;
    const float* Wrow = W + (size_t)(nBase + wr) * HSZ + wk;

    for (int kt = 0; kt < 16; ++kt) {
        const int k0 = kt * 32;
#pragma unroll
        for (int i = 0; i < 8; ++i) As[lk + i][lm] = Arow[k0 + i];
#pragma unroll
        for (int i = 0; i < 16; ++i) Ws[wk + i][wr] = Wrow[k0 + i];
        __syncthreads();
#pragma unroll
        for (int k = 0; k < 32; ++k) {
            float4 a  = *(const float4*)&As[k][m0];
            float4 w0 = *(const float4*)&Ws[k][v0];
            float4 w1 = *(const float4*)&Ws[k][v0 + 4];
            const float av[4] = {a.x, a.y, a.z, a.w};
            const float wv[8] = {w0.x, w0.y, w0.z, w0.w, w1.x, w1.y, w1.z, w1.w};
#pragma unroll
            for (int r = 0; r < 4; ++r)
#pragma unroll
                for (int c = 0; c < 8; ++c) acc[r][c] += av[r] * wv[c];
        }
        __syncthreads();
    }

#pragma unroll
    for (int r = 0; r < 4; ++r) {
        const int m = mBase + m0 + r;
        if (MODE <= 1) {
#pragma unroll
            for (int c = 0; c < 8; ++c) {
                const int n = nBase + v0 + c;
                g_u[m * HSZ + n] = ftanh(acc[r][c] + b[n]);
            }
        } else {
            const float dtv = ts[2 * m + 1] - ts[2 * m];
#pragma unroll
            for (int c = 0; c < 8; ++c) {
                const int n = nBase + v0 + c;
                const int idx = m * HSZ + n;
                const float kv = acc[r][c] + b[n];
                if (MODE == 11) {           // k1
                    accht[idx] = kv;
                    g_h1[idx] = g_h2[idx] + 0.5f * dtv * kv;
                } else if (MODE == 12) {    // k2
                    accht[idx] += 2.0f * kv;
                    g_h1[idx] = g_h2[idx] + 0.5f * dtv * kv;
                } else if (MODE == 13) {    // k3
                    accht[idx] += 2.0f * kv;
                    g_h1[idx] = g_h2[idx] + dtv * kv;
                } else {                    // k4: final ht
                    accht[idx] = g_h2[idx] + dtv * (1.0f / 6.0f) * (accht[idx] + kv);
                }
            }
        }
    }
}

extern "C" void kernel_launch(void* const* d_in, const int* in_sizes, int n_in,
                              void* d_out, int out_size, void* d_ws, size_t ws_size,
                              hipStream_t stream) {
    const float* x   = (const float*)d_in[0];
    const float* h0  = (const float*)d_in[1];
    const float* c0  = (const float*)d_in[2];
    const float* ts  = (const float*)d_in[3];
    const float* Wih = (const float*)d_in[4];
    const float* Whh = (const float*)d_in[5];
    const float* bih = (const float*)d_in[6];
    const float* bhh = (const float*)d_in[7];
    const float* W1  = (const float*)d_in[8];
    const float* b1  = (const float*)d_in[9];
    const float* W2  = (const float*)d_in[10];
    const float* b2  = (const float*)d_in[11];

    float* out_ht = (float*)d_out;
    float* out_c  = out_ht + (size_t)BATCH * HSZ;

    dim3 blk(256);
    dim3 gcell(BATCH / 64, 16);
    dim3 gode(BATCH / 64, 4);

    // two LSTM cell updates (same x)
    cell_kernel<true ><<<gcell, blk, 0, stream>>>(x, h0, c0, Wih, Whh, bih, bhh, out_c);
    cell_kernel<false><<<gcell, blk, 0, stream>>>(x, h0, c0, Wih, Whh, bih, bhh, out_c);

    // RK4: k1..k4
    ode_kernel<0 ><<<gode, blk, 0, stream>>>(W1, b1, ts, out_ht);
    ode_kernel<11><<<gode, blk, 0, stream>>>(W2, b2, ts, out_ht);
    ode_kernel<1 ><<<gode, blk, 0, stream>>>(W1, b1, ts, out_ht);
    ode_kernel<12><<<gode, blk, 0, stream>>>(W2, b2, ts, out_ht);
    ode_kernel<1 ><<<gode, blk, 0, stream>>>(W1, b1, ts, out_ht);
    ode_kernel<13><<<gode, blk, 0, stream>>>(W2, b2, ts, out_ht);
    ode_kernel<1 ><<<gode, blk, 0, stream>>>(W1, b1, ts, out_ht);
    ode_kernel<14><<<gode, blk, 0, stream>>>(W2, b2, ts, out_ht);
}

// Round 2
// 967.347 us; speedup vs baseline: 4.1799x; 4.1799x over previous
//
#include <hip/hip_runtime.h>
#include <math.h>

#define BATCH 32768
#define ISZ   256
#define HSZ   512
#define KC    768   // cell GEMM K = ISZ + HSZ

typedef __attribute__((ext_vector_type(8))) short bf16x8;
typedef __attribute__((ext_vector_type(4))) float f32x4;

// bf16 activation / weight buffers (static to avoid ws_size dependence)
static __device__ unsigned short g_xbf[(size_t)BATCH * ISZ];   // x in bf16
static __device__ unsigned short g_ha [(size_t)BATCH * HSZ];   // h0 -> later h2 (bf16)
static __device__ unsigned short g_hb [(size_t)BATCH * HSZ];   // h1 -> later htmp (bf16)
static __device__ unsigned short g_ub [(size_t)BATCH * HSZ];   // tanh(W1 h + b1) (bf16)
static __device__ float          g_h2f[(size_t)BATCH * HSZ];   // new_h in fp32 (RK additive path)
static __device__ unsigned short g_Wc [2048 * KC];             // [Wih | Whh] bf16, row-major [2048][768]
static __device__ unsigned short g_W1b[HSZ * HSZ];
static __device__ unsigned short g_W2b[HSZ * HSZ];

__device__ __forceinline__ unsigned short f2bf(float f) {
    unsigned int u = __float_as_uint(f);
    u += 0x7fff + ((u >> 16) & 1);   // round-to-nearest-even
    return (unsigned short)(u >> 16);
}
__device__ __forceinline__ float fsigm(float x) { return 1.0f / (1.0f + __expf(-x)); }
__device__ __forceinline__ float ftanh(float x) { return 1.0f - 2.0f / (__expf(2.0f * x) + 1.0f); }

__device__ __forceinline__ void gload16(const void* g, void* l) {
    __builtin_amdgcn_global_load_lds(
        (const __attribute__((address_space(1))) unsigned int*)g,
        (__attribute__((address_space(3))) unsigned int*)l, 16, 0, 0);
}

// ---------------------------------------------------------------------------
// fp32 -> bf16 conversion, float4-vectorized, with row restride (for Wih|Whh
// concat). DST selects the static destination buffer (device-symbol access).
// w4shift: log2(row width / 4).
// ---------------------------------------------------------------------------
template <int DST>
__global__ __launch_bounds__(256) void conv_kernel(
    const float* __restrict__ src, int nv, int w4shift, int dstride, int doff)
{
    unsigned short* __restrict__ dst =
        DST == 0 ? g_xbf : DST == 1 ? g_ha : DST == 2 ? g_Wc : DST == 3 ? g_W1b : g_W2b;
    int i = blockIdx.x * 256 + threadIdx.x;
    const int gs = gridDim.x * 256;
    for (; i < nv; i += gs) {
        const int r = i >> w4shift;
        const int c = i & ((1 << w4shift) - 1);
        const float4 v = ((const float4*)src)[i];
        ushort4 o;
        o.x = f2bf(v.x); o.y = f2bf(v.y); o.z = f2bf(v.z); o.w = f2bf(v.w);
        *(ushort4*)&dst[(size_t)r * dstride + doff + c * 4] = o;
    }
}

// ---------------------------------------------------------------------------
// Unified MFMA GEMM (m97-style 128x128 tile, BK=64, 4 waves, 4x4 frags/wave).
// MODE 0: cell1  z=[x|h0(g_ha)]@Wc^T  -> h1->g_hb,          c: c0->out_c
// MODE 1: cell2  z=[x|h1(g_hb)]@Wc^T  -> h2->g_ha + g_h2f,  c: out_c->out_c
// MODE 2: u = tanh(g_ha @ W1^T + b1) -> g_ub
// MODE 3: u = tanh(g_hb @ W1^T + b1) -> g_ub
// MODE 11..14: k = g_ub @ W2^T + b2 ; RK accumulate in accht, htmp -> g_hb
// Cell N-mapping: block covers 32 j-cols x 4 gates (128 virtual cols); wave-col
// fragment index fn == gate, so the LSTM epilogue is fully in-register.
// ---------------------------------------------------------------------------
template <int MODE>
__global__ __launch_bounds__(256) void gemm_kernel(
    const float* __restrict__ p0, const float* __restrict__ p1,
    const float* __restrict__ p2, float* __restrict__ p3,
    const float* __restrict__ ts, float* __restrict__ accht)
{
    constexpr bool CELL = (MODE <= 1);
    constexpr int KTOT = CELL ? KC : HSZ;
    constexpr int NKT  = KTOT / 64;

    __shared__ __align__(16) unsigned short As[128 * 64];
    __shared__ __align__(16) unsigned short Bs[128 * 64];

    const int tid  = threadIdx.x;
    const int lane = tid & 63;
    const int wid  = tid >> 6;
    const int wr   = wid >> 1, wc = wid & 1;
    const int l15  = lane & 15, lq = lane >> 4;
    const int mBase = blockIdx.x * 128;
    const int nb    = blockIdx.y;

    const unsigned short* __restrict__ Ah;   // A source (h-part for cell, full for ODE)
    const unsigned short* __restrict__ Bsrc;
    if constexpr (MODE == 0)      { Ah = g_ha; Bsrc = g_Wc;  }
    else if constexpr (MODE == 1) { Ah = g_hb; Bsrc = g_Wc;  }
    else if constexpr (MODE == 2) { Ah = g_ha; Bsrc = g_W1b; }
    else if constexpr (MODE == 3) { Ah = g_hb; Bsrc = g_W1b; }
    else                          { Ah = g_ub; Bsrc = g_W2b; }

    // staging mapping: slot s = j*256 + tid; row = s>>3, 16B-chunk = s&7
    const int arow = tid >> 3, ch = tid & 7;
    int bgrow[4];
#pragma unroll
    for (int j = 0; j < 4; ++j) {
        const int vr = j * 32 + arow;
        if constexpr (CELL) {
            const int g    = (vr >> 4) & 3;
            const int jcol = nb * 32 + (vr >> 6) * 16 + (vr & 15);
            bgrow[j] = g * 512 + jcol;
        } else {
            bgrow[j] = nb * 128 + vr;
        }
    }

    f32x4 acc[4][4];
#pragma unroll
    for (int fm = 0; fm < 4; ++fm)
#pragma unroll
        for (int fn = 0; fn < 4; ++fn) acc[fm][fn] = (f32x4){0.f, 0.f, 0.f, 0.f};

    for (int kt = 0; kt < NKT; ++kt) {
        const int k0 = kt * 64;
        // stage A + B tiles (8 x global_load_lds dwordx4 per thread)
#pragma unroll
        for (int j = 0; j < 4; ++j) {
            const int row = j * 32 + arow;
            const unsigned short* ga;
            if constexpr (CELL) {
                ga = (k0 < 256)
                   ? g_xbf + (size_t)(mBase + row) * ISZ + (k0       + ch * 8)
                   : Ah    + (size_t)(mBase + row) * HSZ + (k0 - 256 + ch * 8);
            } else {
                ga = Ah + (size_t)(mBase + row) * HSZ + k0 + ch * 8;
            }
            gload16(ga, (char*)As + j * 4096 + wid * 1024);
            const unsigned short* gb = Bsrc + (size_t)bgrow[j] * KTOT + k0 + ch * 8;
            gload16(gb, (char*)Bs + j * 4096 + wid * 1024);
        }
        __syncthreads();
#pragma unroll
        for (int kk = 0; kk < 2; ++kk) {
            bf16x8 a[4], b[4];
#pragma unroll
            for (int f = 0; f < 4; ++f) {
                const int rowA = wr * 64 + f * 16 + l15;
                a[f] = *(const bf16x8*)((const char*)As + rowA * 128 + kk * 64 + lq * 16);
                const int rowB = wc * 64 + f * 16 + l15;
                b[f] = *(const bf16x8*)((const char*)Bs + rowB * 128 + kk * 64 + lq * 16);
            }
#pragma unroll
            for (int fm = 0; fm < 4; ++fm)
#pragma unroll
                for (int fn = 0; fn < 4; ++fn)
                    acc[fm][fn] = __builtin_amdgcn_mfma_f32_16x16x32_bf16(
                        a[fm], b[fn], acc[fm][fn], 0, 0, 0);
        }
        __syncthreads();
    }

    // ---------------- epilogue ----------------
    if constexpr (CELL) {
        const float* __restrict__ bih = p0;
        const float* __restrict__ bhh = p1;
        const float* __restrict__ c_in = p2;
        float* __restrict__ c_out = p3;
        const int j = nb * 32 + wc * 16 + l15;
        float bsum[4];
#pragma unroll
        for (int g = 0; g < 4; ++g) bsum[g] = bih[g * 512 + j] + bhh[g * 512 + j];
#pragma unroll
        for (int fm = 0; fm < 4; ++fm) {
#pragma unroll
            for (int r = 0; r < 4; ++r) {
                const int m = mBase + wr * 64 + fm * 16 + lq * 4 + r;
                const size_t idx = (size_t)m * HSZ + j;
                const float ig = fsigm(acc[fm][0][r] + bsum[0]);
                const float fg = fsigm(acc[fm][1][r] + bsum[1]);
                const float gg = ftanh(acc[fm][2][r] + bsum[2]);
                const float og = fsigm(acc[fm][3][r] + bsum[3]);
                const float cnew = fg * c_in[idx] + ig * gg;
                const float hnew = og * ftanh(cnew);
                c_out[idx] = cnew;
                if constexpr (MODE == 0) {
                    g_hb[idx] = f2bf(hnew);
                } else {
                    g_ha[idx] = f2bf(hnew);
                    g_h2f[idx] = hnew;
                }
            }
        }
    } else if constexpr (MODE == 2 || MODE == 3) {
        const float* __restrict__ b1 = p0;
#pragma unroll
        for (int fm = 0; fm < 4; ++fm) {
#pragma unroll
            for (int r = 0; r < 4; ++r) {
                const int m = mBase + wr * 64 + fm * 16 + lq * 4 + r;
#pragma unroll
                for (int fn = 0; fn < 4; ++fn) {
                    const int n = nb * 128 + wc * 64 + fn * 16 + l15;
                    g_ub[(size_t)m * HSZ + n] = f2bf(ftanh(acc[fm][fn][r] + b1[n]));
                }
            }
        }
    } else {
        const float* __restrict__ b2 = p0;
#pragma unroll
        for (int fm = 0; fm < 4; ++fm) {
#pragma unroll
            for (int r = 0; r < 4; ++r) {
                const int m = mBase + wr * 64 + fm * 16 + lq * 4 + r;
                const float dtv = ts[2 * m + 1] - ts[2 * m];
#pragma unroll
                for (int fn = 0; fn < 4; ++fn) {
                    const int n = nb * 128 + wc * 64 + fn * 16 + l15;
                    const size_t idx = (size_t)m * HSZ + n;
                    const float kv = acc[fm][fn][r] + b2[n];
                    if constexpr (MODE == 11) {
                        accht[idx] = kv;
                        g_hb[idx] = f2bf(g_h2f[idx] + 0.5f * dtv * kv);
                    } else if constexpr (MODE == 12) {
                        accht[idx] += 2.0f * kv;
                        g_hb[idx] = f2bf(g_h2f[idx] + 0.5f * dtv * kv);
                    } else if constexpr (MODE == 13) {
                        accht[idx] += 2.0f * kv;
                        g_hb[idx] = f2bf(g_h2f[idx] + dtv * kv);
                    } else {
                        accht[idx] = g_h2f[idx] + dtv * (1.0f / 6.0f) * (accht[idx] + kv);
                    }
                }
            }
        }
    }
}

extern "C" void kernel_launch(void* const* d_in, const int* in_sizes, int n_in,
                              void* d_out, int out_size, void* d_ws, size_t ws_size,
                              hipStream_t stream) {
    const float* x   = (const float*)d_in[0];
    const float* h0  = (const float*)d_in[1];
    const float* c0  = (const float*)d_in[2];
    const float* ts  = (const float*)d_in[3];
    const float* Wih = (const float*)d_in[4];
    const float* Whh = (const float*)d_in[5];
    const float* bih = (const float*)d_in[6];
    const float* bhh = (const float*)d_in[7];
    const float* W1  = (const float*)d_in[8];
    const float* b1  = (const float*)d_in[9];
    const float* W2  = (const float*)d_in[10];
    const float* b2  = (const float*)d_in[11];

    float* out_ht = (float*)d_out;
    float* out_c  = out_ht + (size_t)BATCH * HSZ;

    dim3 blk(256);
    // conversions (fp32 -> bf16)
    conv_kernel<0><<<2048, blk, 0, stream>>>(x,   BATCH * ISZ / 4, 6, ISZ, 0);
    conv_kernel<1><<<2048, blk, 0, stream>>>(h0,  BATCH * HSZ / 4, 7, HSZ, 0);
    conv_kernel<2><<<256,  blk, 0, stream>>>(Wih, 2048 * 256 / 4,  6, KC, 0);
    conv_kernel<2><<<256,  blk, 0, stream>>>(Whh, 2048 * 512 / 4,  7, KC, 256);
    conv_kernel<3><<<256,  blk, 0, stream>>>(W1,  HSZ * HSZ / 4,   7, HSZ, 0);
    conv_kernel<4><<<256,  blk, 0, stream>>>(W2,  HSZ * HSZ / 4,   7, HSZ, 0);

    dim3 gcell(BATCH / 128, 16);
    dim3 gode(BATCH / 128, 4);

    // two LSTM cell updates
    gemm_kernel<0><<<gcell, blk, 0, stream>>>(bih, bhh, c0,    out_c, nullptr, nullptr);
    gemm_kernel<1><<<gcell, blk, 0, stream>>>(bih, bhh, out_c, out_c, nullptr, nullptr);

    // RK4
    gemm_kernel<2 ><<<gode, blk, 0, stream>>>(b1, nullptr, nullptr, nullptr, ts, out_ht);
    gemm_kernel<11><<<gode, blk, 0, stream>>>(b2, nullptr, nullptr, nullptr, ts, out_ht);
    gemm_kernel<3 ><<<gode, blk, 0, stream>>>(b1, nullptr, nullptr, nullptr, ts, out_ht);
    gemm_kernel<12><<<gode, blk, 0, stream>>>(b2, nullptr, nullptr, nullptr, ts, out_ht);
    gemm_kernel<3 ><<<gode, blk, 0, stream>>>(b1, nullptr, nullptr, nullptr, ts, out_ht);
    gemm_kernel<13><<<gode, blk, 0, stream>>>(b2, nullptr, nullptr, nullptr, ts, out_ht);
    gemm_kernel<3 ><<<gode, blk, 0, stream>>>(b1, nullptr, nullptr, nullptr, ts, out_ht);
    gemm_kernel<14><<<gode, blk, 0, stream>>>(b2, nullptr, nullptr, nullptr, ts, out_ht);
}